// Round 9
// baseline (177.631 us; speedup 1.0000x reference)
//
#include <hip/hip_runtime.h>

#define H 768
#define W 768
#define SW 256        // output cols per strip
#define RW 272        // region width (SW + 16)
#define ABW 264       // A,b row width (SW + 8)
#define ROWS 48       // output rows per band
#define STEPS 64      // ROWS + 16 single-row steps
#define RADIUS 4

// R8 structure (single-row stream, double-buffered rows, ONE barrier/step,
// clean compile: VGPR 64, zero scratch) with the 12KB xring LDS replaced by a
// u-static register delay ring, and occupancy raised 4 -> 6 blocks/CU.
__global__ __launch_bounds__(256, 6) void gf_stream7(
    const float* __restrict__ xg, const float* __restrict__ yg,
    float* __restrict__ outg)
{
    __shared__ float2 xybuf[2][RW];   // double-buffered x,y row   4352 B
    __shared__ float2 abbuf[2][ABW];  // double-buffered A,b row   4224 B
    __shared__ float4 tring[9][8];    // extra-col h-ring (t<8)    1152 B  (9728 B)

    const int t     = threadIdx.x;
    const int base  = blockIdx.x * SW;
    const int R0    = blockIdx.y * ROWS;
    const int plane = blockIdx.z;

    const float* xp = xg + (size_t)plane * (H * W);
    const float* yp = yg + (size_t)plane * (H * W);
    float*       op = outg + (size_t)plane * (H * W);

    // ---- per-thread column geometry (loop-invariant) ----
    const int  a_abs   = base + t - 4;                  // main A-col
    const bool a_colok = (a_abs >= 0) && (a_abs < W);
    const float invCwA = a_colok
        ? 1.0f / (float)(min(a_abs + RADIUS, W - 1) - max(a_abs - RADIUS, 0) + 1) : 0.f;
    const int  a2_abs   = base + 252 + t;               // extra A-col (t<8)
    const bool a2_colok = (t < 8) && (a2_abs < W);
    const float invCwA2 = a2_colok
        ? 1.0f / (float)(min(a2_abs + RADIUS, W - 1) - max(a2_abs - RADIUS, 0) + 1) : 0.f;
    const int   c_abs  = base + t;                      // output col
    const float invCwO = 1.0f / (float)(min(c_abs + RADIUS, W - 1) - max(c_abs - RADIUS, 0) + 1);
    const int  lc1   = base + t - 8;                    // load col (region col t)
    const bool lc1ok = (lc1 >= 0) && (lc1 < W);
    const int  lc2   = base + 248 + t;                  // load col (region col 256+t), t<16
    const bool lc2ok = (t < 16) && (lc2 < W);

    // ---- register rings (indexed ONLY by the unroll var u => static) ----
    float hx[9], hy[9], hxy[9], hxx[9];   // h-sum history (col a_abs)
    float aA[9], aB[9];                   // A,b h-sum history (col c_abs)
    float xdel[9];                        // x(row processed 8 steps ago, c_abs)
#pragma unroll
    for (int i = 0; i < 9; ++i) { hx[i]=hy[i]=hxy[i]=hxx[i]=0.f; aA[i]=aB[i]=0.f; xdel[i]=0.f; }
    float vx=0.f, vy=0.f, vxy=0.f, vxx=0.f;       // vertical sums (col a_abs)
    float v2x=0.f, v2y=0.f, v2xy=0.f, v2xx=0.f;   // vertical sums (extra col)
    float vA=0.f, vB=0.f;                         // vertical sums of hA,hB

    if (t < 72) ((float4*)tring)[t] = make_float4(0.f,0.f,0.f,0.f);

    // ---- prologue: xybuf[0] <- row R0-8 ; prefetch row R0-7 into regs ----
    {
        int g = R0 - 8;
        bool k = (g >= 0);
        const float *xr_ = xp + g * W, *yr_ = yp + g * W;
        float a = (k && lc1ok) ? xr_[lc1] : 0.f;
        float b = (k && lc1ok) ? yr_[lc1] : 0.f;
        xybuf[0][t] = make_float2(a, b);
        if (t < 16) {
            float c = (k && lc2ok) ? xr_[lc2] : 0.f;
            float d = (k && lc2ok) ? yr_[lc2] : 0.f;
            xybuf[0][256 + t] = make_float2(c, d);
        }
    }
    float px_, py_, px2_, py2_;
    {
        int g = R0 - 7;
        bool k = (g >= 0);
        const float *xr_ = xp + g * W, *yr_ = yp + g * W;
        px_  = (k && lc1ok) ? xr_[lc1] : 0.f;  py_  = (k && lc1ok) ? yr_[lc1] : 0.f;
        px2_ = (k && lc2ok) ? xr_[lc2] : 0.f;  py2_ = (k && lc2ok) ? yr_[lc2] : 0.f;
    }
    __syncthreads();

    for (int S0 = 0; S0 < STEPS; S0 += 9) {
#pragma unroll
        for (int u = 0; u < 9; ++u) {
            const int S = S0 + u;
            if (S < STEPS) {                     // uniform guard
                const int r   = R0 - 16 + S;     // output row this step
                const int cur = S & 1, nxt = cur ^ 1;

                // x(r, c_abs): captured 8 steps ago -> slot (u+1)%9 (read first)
                const float xq = xdel[(u + 1) % 9];

                // -- publish row r+9 (prefetched last step) into the other buffer --
                xybuf[nxt][t] = make_float2(px_, py_);
                if (t < 16) xybuf[nxt][256 + t] = make_float2(px2_, py2_);

                // -- prefetch row r+10 --
                {
                    int g = r + 10;
                    bool k = (g >= 0) && (g < H);
                    const float *xr_ = xp + g * W, *yr_ = yp + g * W;
                    px_  = (k && lc1ok) ? xr_[lc1] : 0.f;  py_  = (k && lc1ok) ? yr_[lc1] : 0.f;
                    px2_ = (k && lc2ok) ? xr_[lc2] : 0.f;  py2_ = (k && lc2ok) ? yr_[lc2] : 0.f;
                }

                // -- NH: 9-tap horizontal sums of row r+8 --
                float nx=0.f, ny=0.f, nxy=0.f, nxx=0.f;
                float2 v9;
#pragma unroll
                for (int d = 0; d < 9; ++d) {
                    v9 = xybuf[cur][t + d];
                    nx += v9.x; ny += v9.y; nxy += v9.x * v9.y; nxx += v9.x * v9.x;
                }
                xdel[u] = v9.x;   // tap d=8 is col c_abs of row r+8
                vx  += nx  - hx[u];  hx[u]  = nx;
                vy  += ny  - hy[u];  hy[u]  = ny;
                vxy += nxy - hxy[u]; hxy[u] = nxy;
                vxx += nxx - hxx[u]; hxx[u] = nxx;

                // -- A,b at image row ra = r+4 (valid from S=8) --
                const int ra = r + 4;
                if (S >= 8) {
                    float A0 = 0.f, B0 = 0.f;
                    if (a_colok && ra >= 0 && ra < H) {
                        const float invCh = 1.0f /
                            (float)(min(ra + RADIUS, H - 1) - max(ra - RADIUS, 0) + 1);
                        float invN = invCh * invCwA;
                        float mx = vx * invN, my = vy * invN;
                        float cov = vxy * invN - mx * my;
                        float vr  = vxx * invN - mx * mx;
                        A0 = cov * __builtin_amdgcn_rcpf(vr + 0.1f);
                        B0 = my - A0 * mx;
                    }
                    abbuf[cur][t] = make_float2(A0, B0);
                }
                // -- extra A-cols (region 260..267), lanes t<8; LDS history ring --
                if (t < 8) {
                    float ex=0.f, ey=0.f, exy=0.f, exx=0.f;
#pragma unroll
                    for (int d = 0; d < 9; ++d) {
                        float2 v = xybuf[cur][256 + t + d];
                        ex += v.x; ey += v.y; exy += v.x * v.y; exx += v.x * v.x;
                    }
                    float4 o = tring[u][t];
                    v2x += ex - o.x; v2y += ey - o.y; v2xy += exy - o.z; v2xx += exx - o.w;
                    tring[u][t] = make_float4(ex, ey, exy, exx);
                    if (S >= 8) {
                        float A2 = 0.f, B2 = 0.f;
                        if (a2_colok && ra >= 0 && ra < H) {
                            const float invCh = 1.0f /
                                (float)(min(ra + RADIUS, H - 1) - max(ra - RADIUS, 0) + 1);
                            float invN = invCh * invCwA2;
                            float mx = v2x * invN, my = v2y * invN;
                            float cov = v2xy * invN - mx * my;
                            float vr  = v2xx * invN - mx * mx;
                            A2 = cov * __builtin_amdgcn_rcpf(vr + 0.1f);
                            B2 = my - A2 * mx;
                        }
                        abbuf[cur][256 + t] = make_float2(A2, B2);
                    }
                }

                __syncthreads();   // the ONLY barrier per step

                // -- O: 9-tap horizontal of A,b + vertical ring + store row r --
                if (S >= 8) {
                    float hA=0.f, hB=0.f;
#pragma unroll
                    for (int d = 0; d < 9; ++d) {
                        float2 v = abbuf[cur][t + d];
                        hA += v.x; hB += v.y;
                    }
                    vA += hA - aA[u]; aA[u] = hA;
                    vB += hB - aB[u]; aB[u] = hB;
                    if (S >= 16) {
                        const float invCh = 1.0f /
                            (float)(min(r + RADIUS, H - 1) - max(r - RADIUS, 0) + 1);
                        float invN = invCh * invCwO;
                        op[r * W + c_abs] = (vA * invN) * xq + (vB * invN);
                    }
                }
            }
        }
    }
}

extern "C" void kernel_launch(void* const* d_in, const int* in_sizes, int n_in,
                              void* d_out, int out_size, void* d_ws, size_t ws_size,
                              hipStream_t stream) {
    const float* x = (const float*)d_in[0];
    const float* y = (const float*)d_in[1];
    float* out = (float*)d_out;

    dim3 grid(W / SW, H / ROWS, 24);   // 3 x 16 x 24 = 1152 blocks (4.5/CU, all resident at 6/CU cap)
    dim3 block(256);
    hipLaunchKernelGGL(gf_stream7, grid, block, 0, stream, x, y, out);
}

// Round 10
// 104.617 us; speedup vs baseline: 1.6979x; 1.6979x over previous
//
#include <hip/hip_runtime.h>

#define H 768
#define W 768
#define SW 256        // output cols per strip
#define RW 272        // region width (SW + 16)
#define ABW 264       // A,b row width (SW + 8)
#define ROWS 32       // output rows per band (small bands -> 6.75 blocks/CU, all resident)
#define STEPS 48      // ROWS + 16 single-row steps
#define RADIUS 4

// Body = R9's LDS-light single-row stream (proven numerics), launch_bounds
// = (256,4): the ONLY clean-compile point. (256,5)/(256,6) both made the
// allocator spill the rings (WRITE_SIZE 269..669 MB of scratch traffic).
__global__ __launch_bounds__(256, 4) void gf_stream8(
    const float* __restrict__ xg, const float* __restrict__ yg,
    float* __restrict__ outg)
{
    __shared__ float2 xybuf[2][RW];   // double-buffered x,y row   4352 B
    __shared__ float2 abbuf[2][ABW];  // double-buffered A,b row   4224 B
    __shared__ float4 tring[9][8];    // extra-col h-ring (t<8)    1152 B  (9728 B)

    const int t     = threadIdx.x;
    const int base  = blockIdx.x * SW;
    const int R0    = blockIdx.y * ROWS;
    const int plane = blockIdx.z;

    const float* xp = xg + (size_t)plane * (H * W);
    const float* yp = yg + (size_t)plane * (H * W);
    float*       op = outg + (size_t)plane * (H * W);

    // ---- per-thread column geometry (loop-invariant) ----
    const int  a_abs   = base + t - 4;                  // main A-col
    const bool a_colok = (a_abs >= 0) && (a_abs < W);
    const float invCwA = a_colok
        ? 1.0f / (float)(min(a_abs + RADIUS, W - 1) - max(a_abs - RADIUS, 0) + 1) : 0.f;
    const int  a2_abs   = base + 252 + t;               // extra A-col (t<8)
    const bool a2_colok = (t < 8) && (a2_abs < W);
    const float invCwA2 = a2_colok
        ? 1.0f / (float)(min(a2_abs + RADIUS, W - 1) - max(a2_abs - RADIUS, 0) + 1) : 0.f;
    const int   c_abs  = base + t;                      // output col
    const float invCwO = 1.0f / (float)(min(c_abs + RADIUS, W - 1) - max(c_abs - RADIUS, 0) + 1);
    const int  lc1   = base + t - 8;                    // load col (region col t)
    const bool lc1ok = (lc1 >= 0) && (lc1 < W);
    const int  lc2   = base + 248 + t;                  // load col (region col 256+t), t<16
    const bool lc2ok = (t < 16) && (lc2 < W);

    // ---- register rings (indexed ONLY by the unroll var u => static) ----
    float hx[9], hy[9], hxy[9], hxx[9];   // h-sum history (col a_abs)
    float aA[9], aB[9];                   // A,b h-sum history (col c_abs)
    float xdel[9];                        // x(row processed 8 steps ago, c_abs)
#pragma unroll
    for (int i = 0; i < 9; ++i) { hx[i]=hy[i]=hxy[i]=hxx[i]=0.f; aA[i]=aB[i]=0.f; xdel[i]=0.f; }
    float vx=0.f, vy=0.f, vxy=0.f, vxx=0.f;       // vertical sums (col a_abs)
    float v2x=0.f, v2y=0.f, v2xy=0.f, v2xx=0.f;   // vertical sums (extra col)
    float vA=0.f, vB=0.f;                         // vertical sums of hA,hB

    if (t < 72) ((float4*)tring)[t] = make_float4(0.f,0.f,0.f,0.f);

    // ---- prologue: xybuf[0] <- row R0-8 ; prefetch row R0-7 into regs ----
    {
        int g = R0 - 8;
        bool k = (g >= 0);
        const float *xr_ = xp + g * W, *yr_ = yp + g * W;
        float a = (k && lc1ok) ? xr_[lc1] : 0.f;
        float b = (k && lc1ok) ? yr_[lc1] : 0.f;
        xybuf[0][t] = make_float2(a, b);
        if (t < 16) {
            float c = (k && lc2ok) ? xr_[lc2] : 0.f;
            float d = (k && lc2ok) ? yr_[lc2] : 0.f;
            xybuf[0][256 + t] = make_float2(c, d);
        }
    }
    float px_, py_, px2_, py2_;
    {
        int g = R0 - 7;
        bool k = (g >= 0);
        const float *xr_ = xp + g * W, *yr_ = yp + g * W;
        px_  = (k && lc1ok) ? xr_[lc1] : 0.f;  py_  = (k && lc1ok) ? yr_[lc1] : 0.f;
        px2_ = (k && lc2ok) ? xr_[lc2] : 0.f;  py2_ = (k && lc2ok) ? yr_[lc2] : 0.f;
    }
    __syncthreads();

    for (int S0 = 0; S0 < STEPS; S0 += 9) {
#pragma unroll
        for (int u = 0; u < 9; ++u) {
            const int S = S0 + u;
            if (S < STEPS) {                     // uniform guard
                const int r   = R0 - 16 + S;     // output row this step
                const int cur = S & 1, nxt = cur ^ 1;

                // x(r, c_abs): captured 8 steps ago -> slot (u+1)%9 (read first)
                const float xq = xdel[(u + 1) % 9];

                // -- publish row r+9 (prefetched last step) into the other buffer --
                xybuf[nxt][t] = make_float2(px_, py_);
                if (t < 16) xybuf[nxt][256 + t] = make_float2(px2_, py2_);

                // -- prefetch row r+10 --
                {
                    int g = r + 10;
                    bool k = (g >= 0) && (g < H);
                    const float *xr_ = xp + g * W, *yr_ = yp + g * W;
                    px_  = (k && lc1ok) ? xr_[lc1] : 0.f;  py_  = (k && lc1ok) ? yr_[lc1] : 0.f;
                    px2_ = (k && lc2ok) ? xr_[lc2] : 0.f;  py2_ = (k && lc2ok) ? yr_[lc2] : 0.f;
                }

                // -- NH: 9-tap horizontal sums of row r+8 --
                float nx=0.f, ny=0.f, nxy=0.f, nxx=0.f;
                float2 v9;
#pragma unroll
                for (int d = 0; d < 9; ++d) {
                    v9 = xybuf[cur][t + d];
                    nx += v9.x; ny += v9.y; nxy += v9.x * v9.y; nxx += v9.x * v9.x;
                }
                xdel[u] = v9.x;   // tap d=8 is col c_abs of row r+8
                vx  += nx  - hx[u];  hx[u]  = nx;
                vy  += ny  - hy[u];  hy[u]  = ny;
                vxy += nxy - hxy[u]; hxy[u] = nxy;
                vxx += nxx - hxx[u]; hxx[u] = nxx;

                // -- A,b at image row ra = r+4 (valid from S=8) --
                const int ra = r + 4;
                if (S >= 8) {
                    float A0 = 0.f, B0 = 0.f;
                    if (a_colok && ra >= 0 && ra < H) {
                        const float invCh = 1.0f /
                            (float)(min(ra + RADIUS, H - 1) - max(ra - RADIUS, 0) + 1);
                        float invN = invCh * invCwA;
                        float mx = vx * invN, my = vy * invN;
                        float cov = vxy * invN - mx * my;
                        float vr  = vxx * invN - mx * mx;
                        A0 = cov * __builtin_amdgcn_rcpf(vr + 0.1f);
                        B0 = my - A0 * mx;
                    }
                    abbuf[cur][t] = make_float2(A0, B0);
                }
                // -- extra A-cols (region 260..267), lanes t<8; LDS history ring --
                if (t < 8) {
                    float ex=0.f, ey=0.f, exy=0.f, exx=0.f;
#pragma unroll
                    for (int d = 0; d < 9; ++d) {
                        float2 v = xybuf[cur][256 + t + d];
                        ex += v.x; ey += v.y; exy += v.x * v.y; exx += v.x * v.x;
                    }
                    float4 o = tring[u][t];
                    v2x += ex - o.x; v2y += ey - o.y; v2xy += exy - o.z; v2xx += exx - o.w;
                    tring[u][t] = make_float4(ex, ey, exy, exx);
                    if (S >= 8) {
                        float A2 = 0.f, B2 = 0.f;
                        if (a2_colok && ra >= 0 && ra < H) {
                            const float invCh = 1.0f /
                                (float)(min(ra + RADIUS, H - 1) - max(ra - RADIUS, 0) + 1);
                            float invN = invCh * invCwA2;
                            float mx = v2x * invN, my = v2y * invN;
                            float cov = v2xy * invN - mx * my;
                            float vr  = v2xx * invN - mx * mx;
                            A2 = cov * __builtin_amdgcn_rcpf(vr + 0.1f);
                            B2 = my - A2 * mx;
                        }
                        abbuf[cur][256 + t] = make_float2(A2, B2);
                    }
                }

                __syncthreads();   // the ONLY barrier per step

                // -- O: 9-tap horizontal of A,b + vertical ring + store row r --
                if (S >= 8) {
                    float hA=0.f, hB=0.f;
#pragma unroll
                    for (int d = 0; d < 9; ++d) {
                        float2 v = abbuf[cur][t + d];
                        hA += v.x; hB += v.y;
                    }
                    vA += hA - aA[u]; aA[u] = hA;
                    vB += hB - aB[u]; aB[u] = hB;
                    if (S >= 16) {
                        const float invCh = 1.0f /
                            (float)(min(r + RADIUS, H - 1) - max(r - RADIUS, 0) + 1);
                        float invN = invCh * invCwO;
                        op[r * W + c_abs] = (vA * invN) * xq + (vB * invN);
                    }
                }
            }
        }
    }
}

extern "C" void kernel_launch(void* const* d_in, const int* in_sizes, int n_in,
                              void* d_out, int out_size, void* d_ws, size_t ws_size,
                              hipStream_t stream) {
    const float* x = (const float*)d_in[0];
    const float* y = (const float*)d_in[1];
    float* out = (float*)d_out;

    dim3 grid(W / SW, H / ROWS, 24);   // 3 x 24 x 24 = 1728 blocks (6.75/CU, all resident)
    dim3 block(256);
    hipLaunchKernelGGL(gf_stream8, grid, block, 0, stream, x, y, out);
}